// Round 1
// baseline (299.630 us; speedup 1.0000x reference)
//
#include <hip/hip_runtime.h>

#define TTOT 16384        // 4 * 4096 tokens
#define DDIM 2048
#define NEXP 64
#define TPB  32           // tokens per block
#define SLICE 128         // d staged per slice
#define NSLICE (DDIM / SLICE)
#define XPAD 36           // LDS x-row: 32 tok + 4 pad (floats)
#define LPAD 67           // combine-buffer row (doubles)

// Block = 512 thr (8 waves) owns 32 tokens x 64 experts. Waves interleave
// 16-d chunks of a 128-d LDS slice (double-buffered). x staged TRANSPOSED
// [d][tok]: compute read = 2x ds_read_b128, 4 distinct bank-quads + 16-way
// same-address broadcast (free); staging writes 2-way (free). W: per-lane
// dwordx4 from L1 (T=8 token reuse -> 4.2 MB/CU = L1 floor; R6 showed L1
// doesn't dedup, so reuse must be in registers). Per lane: T=8 x E=4 block,
// fp32 chains per 16-d chunk + fp64 across chunks (proven numerics). 8-wave
// fp64 combine in LDS, then proven shuffle softmax/top-2.
__global__ __launch_bounds__(512, 4)
void moe_router(const float* __restrict__ x, const float* __restrict__ W,
                float* __restrict__ out)
{
    __shared__ float  xs[2][SLICE][XPAD];   // 36.9 KB
    __shared__ double L[TPB][LPAD];         // 17.2 KB
    const int tid  = threadIdx.x;
    const int lane = tid & 63;
    const int wq   = __builtin_amdgcn_readfirstlane(tid >> 6);  // 0..7
    const int eg   = lane & 15;       // experts [4eg, 4eg+4)
    const int tg   = lane >> 4;       // tokens  [8tg, 8tg+8)
    const int tokBase = blockIdx.x * TPB;

    // stager map: q = r*512 + tid -> token = q&31 (=tid&31), dq = q>>5
    const int st  = tid & 31;               // token row this thread stages
    const int sd0 = (tid >> 5) << 2;        // d-offset for r=0 (floats)
    const float* sx = x + (size_t)(tokBase + st) * DDIM;

    double acc64[8][4];
#pragma unroll
    for (int t = 0; t < 8; ++t)
#pragma unroll
        for (int j = 0; j < 4; ++j) acc64[t][j] = 0.0;

    // stage slice 0
    {
        float4 g0 = *(const float4*)(sx + sd0);
        float4 g1 = *(const float4*)(sx + 64 + sd0);
        const float v0[4] = {g0.x, g0.y, g0.z, g0.w};
        const float v1[4] = {g1.x, g1.y, g1.z, g1.w};
#pragma unroll
        for (int j = 0; j < 4; ++j) {
            xs[0][sd0 + j][st]      = v0[j];
            xs[0][64 + sd0 + j][st] = v1[j];
        }
    }
    __syncthreads();

    int buf = 0;
    for (int s = 0; s < NSLICE; ++s) {
        // issue next slice's global loads early (vmcnt in flight over compute)
        float4 g0, g1;
        if (s + 1 < NSLICE) {
            const float* nx = sx + (s + 1) * SLICE;
            g0 = *(const float4*)(nx + sd0);
            g1 = *(const float4*)(nx + 64 + sd0);
        }

        // compute this wave's 16-d chunk
        const int dbase = wq * 16;
        const float* Wp = W + (size_t)(s * SLICE + dbase) * NEXP + 4 * eg;
        float a32[8][4];
#pragma unroll
        for (int t = 0; t < 8; ++t)
#pragma unroll
            for (int j = 0; j < 4; ++j) a32[t][j] = 0.0f;

#pragma unroll 2
        for (int dd = 0; dd < 16; ++dd) {
            const float4 xa = *(const float4*)&xs[buf][dbase + dd][8 * tg];
            const float4 xb = *(const float4*)&xs[buf][dbase + dd][8 * tg + 4];
            const float4 w  = *(const float4*)(Wp + (size_t)dd * NEXP);
            const float xt[8] = {xa.x, xa.y, xa.z, xa.w, xb.x, xb.y, xb.z, xb.w};
            const float wj[4] = {w.x, w.y, w.z, w.w};
#pragma unroll
            for (int t = 0; t < 8; ++t)
#pragma unroll
                for (int j = 0; j < 4; ++j)
                    a32[t][j] = fmaf(xt[t], wj[j], a32[t][j]);
        }
#pragma unroll
        for (int t = 0; t < 8; ++t)
#pragma unroll
            for (int j = 0; j < 4; ++j) acc64[t][j] += (double)a32[t][j];

        // write next slice into the other buffer, one barrier per slice
        if (s + 1 < NSLICE) {
            const int nb = buf ^ 1;
            const float v0[4] = {g0.x, g0.y, g0.z, g0.w};
            const float v1[4] = {g1.x, g1.y, g1.z, g1.w};
#pragma unroll
            for (int j = 0; j < 4; ++j) {
                xs[nb][sd0 + j][st]      = v0[j];
                xs[nb][64 + sd0 + j][st] = v1[j];
            }
            __syncthreads();
            buf = nb;
        }
    }
    __syncthreads();

    // combine the 8 waves' fp64 partials in LDS (sequential, one-time)
    for (int w = 0; w < 8; ++w) {
        if (wq == w) {
#pragma unroll
            for (int t = 0; t < 8; ++t)
#pragma unroll
                for (int j = 0; j < 4; ++j) {
                    if (w == 0) L[8 * tg + t][4 * eg + j] = acc64[t][j];
                    else        L[8 * tg + t][4 * eg + j] += acc64[t][j];
                }
        }
        __syncthreads();
    }

    float* dispatch = out;
    float* probs    = out + (size_t)TTOT * NEXP;
    float* tkp      = out + (size_t)2 * TTOT * NEXP;
    float* tki      = tkp + (size_t)TTOT * 2;

    // each wave: softmax + top-2 for 4 tokens, lane = expert (proven code)
#pragma unroll
    for (int tt = 0; tt < 4; ++tt) {
        const int te = wq * 4 + tt;
        const int gt = tokBase + te;
        const float Lg = (float)L[te][lane];

        float m = Lg;
#pragma unroll
        for (int off = 32; off; off >>= 1) m = fmaxf(m, __shfl_xor(m, off, 64));
        const float p = expf(Lg - m);
        float sden = p;
#pragma unroll
        for (int off = 32; off; off >>= 1) sden += __shfl_xor(sden, off, 64);
        const float prob = p / sden;

        // top-1 (ties -> lowest index, matching lax.top_k / np)
        float v1 = prob; int i1 = lane;
#pragma unroll
        for (int off = 32; off; off >>= 1) {
            const float ov = __shfl_xor(v1, off, 64);
            const int   oi = __shfl_xor(i1, off, 64);
            if (ov > v1 || (ov == v1 && oi < i1)) { v1 = ov; i1 = oi; }
        }
        // top-2
        float v2 = (lane == i1) ? -1.0f : prob; int i2 = lane;
#pragma unroll
        for (int off = 32; off; off >>= 1) {
            const float ov = __shfl_xor(v2, off, 64);
            const int   oi = __shfl_xor(i2, off, 64);
            if (ov > v2 || (ov == v2 && oi < i2)) { v2 = ov; i2 = oi; }
        }

        probs[(size_t)gt * NEXP + lane]    = prob;
        dispatch[(size_t)gt * NEXP + lane] = (lane == i1 || lane == i2) ? 1.0f : 0.0f;
        if (lane == 0) {
            tkp[(size_t)gt * 2 + 0] = v1;
            tkp[(size_t)gt * 2 + 1] = v2;
            tki[(size_t)gt * 2 + 0] = (float)i1;
            tki[(size_t)gt * 2 + 1] = (float)i2;
        }
    }
}

extern "C" void kernel_launch(void* const* d_in, const int* in_sizes, int n_in,
                              void* d_out, int out_size, void* d_ws, size_t ws_size,
                              hipStream_t stream) {
    const float* x = (const float*)d_in[0];
    const float* W = (const float*)d_in[1];
    float* out = (float*)d_out;
    moe_router<<<TTOT / TPB, 512, 0, stream>>>(x, W, out);
}